// Round 1
// baseline (269.325 us; speedup 1.0000x reference)
//
#include <hip/hip_runtime.h>

// out[b, c, w, f] = X[b, c, f*HOP + w]
// B=16, C=2, T=262144, WINDOW=1024, HOP=256, NF=1021
#define WINDOW_SZ 1024
#define HOP_SZ    256
#define NFRAMES   1021
#define T_LEN     262144

__global__ void frame_gather_kernel(const float* __restrict__ X,
                                    float* __restrict__ out) {
    const int f  = blockIdx.x * blockDim.x + threadIdx.x;  // frame index (innermost out dim)
    const int w  = blockIdx.y;                             // window position
    const int bc = blockIdx.z;                             // fused batch*channel (32)
    if (f >= NFRAMES) return;

    // coalesced write along f; read strided by HOP floats (cache-served re-reads)
    out[((size_t)bc * WINDOW_SZ + w) * NFRAMES + f] =
        X[(size_t)bc * T_LEN + (size_t)f * HOP_SZ + w];
}

extern "C" void kernel_launch(void* const* d_in, const int* in_sizes, int n_in,
                              void* d_out, int out_size, void* d_ws, size_t ws_size,
                              hipStream_t stream) {
    const float* X = (const float*)d_in[0];
    float* out = (float*)d_out;

    dim3 block(256, 1, 1);
    dim3 grid((NFRAMES + 255) / 256, WINDOW_SZ, 32);
    frame_gather_kernel<<<grid, block, 0, stream>>>(X, out);
}

// Round 2
// 167.631 us; speedup vs baseline: 1.6067x; 1.6067x over previous
//
#include <hip/hip_runtime.h>

// out[b, c, w, f] = X[b, c, f*HOP + w]
// B=16, C=2, T=262144, WINDOW=1024, HOP=256, NF=1021
// This is a transpose: out column f == contiguous chunk X[f*HOP .. f*HOP+WINDOW).
#define WINDOW_SZ 1024
#define HOP_SZ    256
#define NFRAMES   1021
#define T_LEN     262144

#define FT 64            // frames per tile
#define WT 64            // window positions per tile
#define LDS_STRIDE 65    // +1 pad: scalar LDS ops -> conflict-free transpose

__global__ __launch_bounds__(256)
void frame_transpose_kernel(const float* __restrict__ X,
                            float* __restrict__ out) {
    __shared__ float lds[WT * LDS_STRIDE];   // lds[w_local][f_local], 16.6 KB

    const int tid = threadIdx.x;
    const int f0  = blockIdx.x * FT;   // frame-tile origin
    const int w0  = blockIdx.y * WT;   // window-tile origin
    const int bc  = blockIdx.z;        // fused batch*channel

    const float* Xbc = X + (size_t)bc * T_LEN;

    // ---- load phase: coalesced float4 reads along w, transpose into LDS ----
    // 64 segments (one per f_local) x 16 float4 (covering 64 w) = 1024 tasks, 4/thread
    {
        const int j = tid & 15;   // w-quad index
        int seg     = tid >> 4;   // f_local, 0..15, +16 per pass
#pragma unroll
        for (int p = 0; p < 4; ++p, seg += 16) {
            const int f = f0 + seg;
            if (f < NFRAMES) {
                const float4 v = *(const float4*)(Xbc + (size_t)f * HOP_SZ + w0 + 4 * j);
                const int wl = 4 * j;
                // banks (4j + k + seg) % 32 across the wave -> 2-way only (free)
                lds[(wl + 0) * LDS_STRIDE + seg] = v.x;
                lds[(wl + 1) * LDS_STRIDE + seg] = v.y;
                lds[(wl + 2) * LDS_STRIDE + seg] = v.z;
                lds[(wl + 3) * LDS_STRIDE + seg] = v.w;
            }
        }
    }

    __syncthreads();

    // ---- store phase: scalar stores, 64 lanes cover 256 B contiguous in f ----
    {
        const int fl = tid & 63;   // f_local: lane -> consecutive f (coalesced)
        const int wg = tid >> 6;   // 0..3: which block of 16 output rows
        const int f  = f0 + fl;
        if (f < NFRAMES) {
            float* obase = out + ((size_t)bc * WINDOW_SZ + (w0 + wg * 16)) * (size_t)NFRAMES + f;
#pragma unroll
            for (int r = 0; r < 16; ++r) {
                // LDS read banks (fl + 65*w) % 32 -> 2-way only (free)
                obase[(size_t)r * NFRAMES] = lds[(wg * 16 + r) * LDS_STRIDE + fl];
            }
        }
    }
}

extern "C" void kernel_launch(void* const* d_in, const int* in_sizes, int n_in,
                              void* d_out, int out_size, void* d_ws, size_t ws_size,
                              hipStream_t stream) {
    const float* X = (const float*)d_in[0];
    float* out = (float*)d_out;

    dim3 block(256, 1, 1);
    dim3 grid((NFRAMES + FT - 1) / FT,   // 16 frame tiles
              WINDOW_SZ / WT,            // 16 window tiles
              32);                       // b*c slabs
    frame_transpose_kernel<<<grid, block, 0, stream>>>(X, out);
}